// Round 5
// baseline (34.777 us; speedup 1.0000x reference)
//
#include <hip/hip_runtime.h>

#define BATCH 1024
#define NUM_GENES 20000
#define NONGENE_DIM 64
#define EMB_DIM 32
#define INPUT_DIM (NUM_GENES + NONGENE_DIM)   // 20064
#define G4 (NUM_GENES / 4)                    // 5000 float4 per output row
#define IN4 (INPUT_DIM / 4)                   // 5016 float4 per input row

// ws layout: [0 .. NUM_GENES)             gene_term[g]
//            [NUM_GENES .. NUM_GENES+B)   ng_term[i] + b
#define GENE_THREADS (NUM_GENES * 8)              // 160000
#define NG_THREADS   (BATCH * 16)                 // 16384
#define PRE_TOTAL    (GENE_THREADS + NG_THREADS)  // 176384 = 689 * 256

__global__ __launch_bounds__(256)
void dlge_precompute(const float* __restrict__ x,
                     const float* __restrict__ emb,
                     const float* __restrict__ W,
                     const float* __restrict__ bptr,
                     float* __restrict__ ws) {
    const int tid = blockIdx.x * blockDim.x + threadIdx.x;

    if (tid < GENE_THREADS) {
        // gene_term[g] = dot(emb[g,:], W[65:97]); 8 lanes/gene, coalesced.
        const int g = tid >> 3;
        const int k = tid & 7;
        const float4 e = reinterpret_cast<const float4*>(emb)[g * (EMB_DIM / 4) + k];
        float p = e.x * W[NONGENE_DIM + 1 + 4 * k + 0]
                + e.y * W[NONGENE_DIM + 1 + 4 * k + 1]
                + e.z * W[NONGENE_DIM + 1 + 4 * k + 2]
                + e.w * W[NONGENE_DIM + 1 + 4 * k + 3];
        p += __shfl_down(p, 4, 8);
        p += __shfl_down(p, 2, 8);
        p += __shfl_down(p, 1, 8);
        if (k == 0) ws[g] = p;
    } else if (tid < PRE_TOTAL) {
        // ng_term[row] + b; 16 lanes/row, coalesced 256B per row.
        const int t   = tid - GENE_THREADS;
        const int row = t >> 4;
        const int k   = t & 15;
        const float4 v = reinterpret_cast<const float4*>(
            x + (size_t)row * INPUT_DIM + NUM_GENES)[k];
        float p = v.x * W[4 * k + 0] + v.y * W[4 * k + 1]
                + v.z * W[4 * k + 2] + v.w * W[4 * k + 3];
        p += __shfl_down(p, 8, 16);
        p += __shfl_down(p, 4, 16);
        p += __shfl_down(p, 2, 16);
        p += __shfl_down(p, 1, 16);
        if (k == 0) ws[NUM_GENES + row] = p + bptr[0];
    }
}

// Main pass: PERSISTENT grid. 2048 blocks (8/CU, all co-resident) grid-stride
// over the flat float4 range with a 1-chunk prefetch pipeline: waves live for
// the whole kernel (no block ramp/drain turnover), loads for chunk i+1 are in
// flight while chunk i is stored. Same linear global sweep as before.
#define F4_TOTAL   (BATCH * G4)               // 5,120,000
#define MAIN_BLOCKS 2048
#define STRIDE     (MAIN_BLOCKS * 256)        // 524,288 float4 per sweep
#define N_ITER     10                         // ceil(5120000 / 524288)

__global__ __launch_bounds__(256, 8)
void dlge_main(const float* __restrict__ x,
               const float* __restrict__ ws,
               const float* __restrict__ W,
               float* __restrict__ y) {
    const float wx = W[NONGENE_DIM];
    const float4* __restrict__ xf4  = reinterpret_cast<const float4*>(x);
    const float4* __restrict__ gtf4 = reinterpret_cast<const float4*>(ws);
    float4* __restrict__ yf4        = reinterpret_cast<float4*>(y);

    int idx = blockIdx.x * 256 + threadIdx.x;      // chunk 0 index (< STRIDE)

    // preload chunk 0 (always valid)
    unsigned row = (unsigned)idx / (unsigned)G4;
    int      col = idx - (int)row * G4;
    float4   xv  = xf4[(size_t)row * IN4 + col];
    float4   gv  = gtf4[col];
    float    sv  = ws[NUM_GENES + row];

    for (int i = 0; i < N_ITER - 1; ++i) {
        const int  nidx = idx + STRIDE;
        const bool nv   = (nidx < F4_TOTAL);       // false only on last prefetch tail
        unsigned nrow = 0; int ncol = 0;
        float4 nxv = {0.f, 0.f, 0.f, 0.f};
        float4 ngv = {0.f, 0.f, 0.f, 0.f};
        float  nsv = 0.f;
        if (nv) {
            nrow = (unsigned)nidx / (unsigned)G4;
            ncol = nidx - (int)nrow * G4;
            nxv  = xf4[(size_t)nrow * IN4 + ncol];
            ngv  = gtf4[ncol];
            nsv  = ws[NUM_GENES + nrow];
        }
        // compute + store current chunk while next chunk's loads are in flight
        float4 o;
        o.x = sv + xv.x * wx + gv.x;
        o.y = sv + xv.y * wx + gv.y;
        o.z = sv + xv.z * wx + gv.z;
        o.w = sv + xv.w * wx + gv.w;
        yf4[(size_t)row * G4 + col] = o;

        idx = nidx; row = nrow; col = ncol; xv = nxv; gv = ngv; sv = nsv;
    }

    if (idx < F4_TOTAL) {
        float4 o;
        o.x = sv + xv.x * wx + gv.x;
        o.y = sv + xv.y * wx + gv.y;
        o.z = sv + xv.z * wx + gv.z;
        o.w = sv + xv.w * wx + gv.w;
        yf4[(size_t)row * G4 + col] = o;
    }
}

extern "C" void kernel_launch(void* const* d_in, const int* in_sizes, int n_in,
                              void* d_out, int out_size, void* d_ws, size_t ws_size,
                              hipStream_t stream) {
    const float* x   = (const float*)d_in[0];
    const float* emb = (const float*)d_in[1];
    const float* W   = (const float*)d_in[2];
    const float* b   = (const float*)d_in[3];
    float* y  = (float*)d_out;
    float* ws = (float*)d_ws;

    dlge_precompute<<<PRE_TOTAL / 256, 256, 0, stream>>>(x, emb, W, b, ws);
    dlge_main<<<MAIN_BLOCKS, 256, 0, stream>>>(x, ws, W, y);
}

// Round 7
// 34.704 us; speedup vs baseline: 1.0021x; 1.0021x over previous
//
#include <hip/hip_runtime.h>

#define BATCH 1024
#define NUM_GENES 20000
#define NONGENE_DIM 64
#define EMB_DIM 32
#define INPUT_DIM (NUM_GENES + NONGENE_DIM)   // 20064
#define G4 (NUM_GENES / 4)                    // 5000 float4 per output row
#define IN4 (INPUT_DIM / 4)                   // 5016 float4 per input row

typedef float floatx4 __attribute__((ext_vector_type(4)));  // builtin-compatible

// ws layout: [0 .. NUM_GENES)             gene_term[g]
//            [NUM_GENES .. NUM_GENES+B)   ng_term[i] + b
#define GENE_THREADS (NUM_GENES * 8)              // 160000
#define NG_THREADS   (BATCH * 16)                 // 16384
#define PRE_TOTAL    (GENE_THREADS + NG_THREADS)  // 176384 = 689 * 256

__global__ __launch_bounds__(256)
void dlge_precompute(const float* __restrict__ x,
                     const float* __restrict__ emb,
                     const float* __restrict__ W,
                     const float* __restrict__ bptr,
                     float* __restrict__ ws) {
    const int tid = blockIdx.x * blockDim.x + threadIdx.x;

    if (tid < GENE_THREADS) {
        // gene_term[g] = dot(emb[g,:], W[65:97]); 8 lanes/gene, coalesced.
        const int g = tid >> 3;
        const int k = tid & 7;
        const float4 e = reinterpret_cast<const float4*>(emb)[g * (EMB_DIM / 4) + k];
        float p = e.x * W[NONGENE_DIM + 1 + 4 * k + 0]
                + e.y * W[NONGENE_DIM + 1 + 4 * k + 1]
                + e.z * W[NONGENE_DIM + 1 + 4 * k + 2]
                + e.w * W[NONGENE_DIM + 1 + 4 * k + 3];
        p += __shfl_down(p, 4, 8);
        p += __shfl_down(p, 2, 8);
        p += __shfl_down(p, 1, 8);
        if (k == 0) ws[g] = p;
    } else if (tid < PRE_TOTAL) {
        // ng_term[row] + b; 16 lanes/row, coalesced 256B per row.
        const int t   = tid - GENE_THREADS;
        const int row = t >> 4;
        const int k   = t & 15;
        const float4 v = reinterpret_cast<const float4*>(
            x + (size_t)row * INPUT_DIM + NUM_GENES)[k];
        float p = v.x * W[4 * k + 0] + v.y * W[4 * k + 1]
                + v.z * W[4 * k + 2] + v.w * W[4 * k + 3];
        p += __shfl_down(p, 8, 16);
        p += __shfl_down(p, 4, 16);
        p += __shfl_down(p, 2, 16);
        p += __shfl_down(p, 1, 16);
        if (k == 0) ws[NUM_GENES + row] = p + bptr[0];
    }
}

// Main pass: persistent linear sweep (structure unchanged vs R5) with ONE
// change: y stores are NONTEMPORAL (global_store_dwordx4 nt) so the
// write-once output doesn't allocate in L2/L3 and evict the x read stream.
#define F4_TOTAL   (BATCH * G4)               // 5,120,000
#define MAIN_BLOCKS 2048
#define STRIDE     (MAIN_BLOCKS * 256)        // 524,288 float4 per sweep
#define N_ITER     10                         // ceil(5120000 / 524288)

__global__ __launch_bounds__(256, 8)
void dlge_main(const float* __restrict__ x,
               const float* __restrict__ ws,
               const float* __restrict__ W,
               float* __restrict__ y) {
    const float wx = W[NONGENE_DIM];
    const float4* __restrict__ xf4  = reinterpret_cast<const float4*>(x);
    const float4* __restrict__ gtf4 = reinterpret_cast<const float4*>(ws);
    floatx4* __restrict__ yf4       = reinterpret_cast<floatx4*>(y);

    int idx = blockIdx.x * 256 + threadIdx.x;      // chunk 0 index (< STRIDE)

    // preload chunk 0 (always valid)
    unsigned row = (unsigned)idx / (unsigned)G4;
    int      col = idx - (int)row * G4;
    float4   xv  = xf4[(size_t)row * IN4 + col];
    float4   gv  = gtf4[col];
    float    sv  = ws[NUM_GENES + row];

    for (int i = 0; i < N_ITER - 1; ++i) {
        const int  nidx = idx + STRIDE;
        const bool nv   = (nidx < F4_TOTAL);       // false only on last prefetch tail
        unsigned nrow = 0; int ncol = 0;
        float4 nxv = {0.f, 0.f, 0.f, 0.f};
        float4 ngv = {0.f, 0.f, 0.f, 0.f};
        float  nsv = 0.f;
        if (nv) {
            nrow = (unsigned)nidx / (unsigned)G4;
            ncol = nidx - (int)nrow * G4;
            nxv  = xf4[(size_t)nrow * IN4 + ncol];
            ngv  = gtf4[ncol];
            nsv  = ws[NUM_GENES + nrow];
        }
        // compute + store current chunk while next chunk's loads are in flight
        floatx4 o;
        o.x = sv + xv.x * wx + gv.x;
        o.y = sv + xv.y * wx + gv.y;
        o.z = sv + xv.z * wx + gv.z;
        o.w = sv + xv.w * wx + gv.w;
        __builtin_nontemporal_store(o, &yf4[(size_t)row * G4 + col]);

        idx = nidx; row = nrow; col = ncol; xv = nxv; gv = ngv; sv = nsv;
    }

    if (idx < F4_TOTAL) {
        floatx4 o;
        o.x = sv + xv.x * wx + gv.x;
        o.y = sv + xv.y * wx + gv.y;
        o.z = sv + xv.z * wx + gv.z;
        o.w = sv + xv.w * wx + gv.w;
        __builtin_nontemporal_store(o, &yf4[(size_t)row * G4 + col]);
    }
}

extern "C" void kernel_launch(void* const* d_in, const int* in_sizes, int n_in,
                              void* d_out, int out_size, void* d_ws, size_t ws_size,
                              hipStream_t stream) {
    const float* x   = (const float*)d_in[0];
    const float* emb = (const float*)d_in[1];
    const float* W   = (const float*)d_in[2];
    const float* b   = (const float*)d_in[3];
    float* y  = (float*)d_out;
    float* ws = (float*)d_ws;

    dlge_precompute<<<PRE_TOTAL / 256, 256, 0, stream>>>(x, emb, W, b, ws);
    dlge_main<<<MAIN_BLOCKS, 256, 0, stream>>>(x, ws, W, y);
}